// Round 1
// baseline (677.967 us; speedup 1.0000x reference)
//
#include <hip/hip_runtime.h>
#include <hip/hip_bf16.h>

typedef __hip_bfloat16 bf16;
typedef __attribute__((ext_vector_type(8))) short bf16x8;   // 8 bf16 = 4 VGPRs
typedef __attribute__((ext_vector_type(4))) float f32x4;
typedef __attribute__((ext_vector_type(4))) int int4v;

#define AS1 __attribute__((address_space(1)))
#define AS3 __attribute__((address_space(3)))

#define MDIM 8192   // B*S
#define NDIM 4096   // D_OUT
#define KDIM 4096   // D_IN
#define SCALING 2.0f
#define NT (KDIM / 64)   // 64 K-tiles of BK=64

// ---------------------------------------------------------------------------
// prep: fused fold (Weff = W + s*B@A + mask?delta) + X fp32->bf16 convert.
// Blocks [0, 8192): fold.  Blocks [8192, 24576): convert.
// Both memory-bound; fusing removes one launch bubble and lets the tail of
// one fill the other's BW.
// ---------------------------------------------------------------------------
__global__ __launch_bounds__(256) void prep(
    const float* __restrict__ W, const float* __restrict__ lA,
    const float* __restrict__ lB, const float* __restrict__ delta,
    const int* __restrict__ mask, bf16* __restrict__ Weff,
    const float* __restrict__ X, bf16* __restrict__ Xb)
{
    const int bid = blockIdx.x;
    if (bid < 8192) {
        // ---- fold Weff ----
        int idx = bid * 256 + threadIdx.x;           // 2,097,152 total
        int o   = idx >> 9;                          // 512 threads per row of 4096
        int d0  = (idx & 511) << 3;
        size_t base = (size_t)o * KDIM + d0;

        float Bo[16];
#pragma unroll
        for (int r = 0; r < 16; ++r) Bo[r] = lB[o * 16 + r];

        f32x4 wa = *(const f32x4*)(W + base);
        f32x4 wb = *(const f32x4*)(W + base + 4);
        f32x4 da = *(const f32x4*)(delta + base);
        f32x4 db = *(const f32x4*)(delta + base + 4);

        int mk[8];
        *(int4v*)(mk)     = *(const int4v*)(mask + base);
        *(int4v*)(mk + 4) = *(const int4v*)(mask + base + 4);

        float lor[8] = {0.f, 0.f, 0.f, 0.f, 0.f, 0.f, 0.f, 0.f};
#pragma unroll
        for (int r = 0; r < 16; ++r) {
            f32x4 aa = *(const f32x4*)(lA + (size_t)r * KDIM + d0);
            f32x4 ab = *(const f32x4*)(lA + (size_t)r * KDIM + d0 + 4);
#pragma unroll
            for (int e = 0; e < 4; ++e) {
                lor[e]     += Bo[r] * aa[e];
                lor[e + 4] += Bo[r] * ab[e];
            }
        }

        int4v ov4;
        bf16* ov = (bf16*)&ov4;
#pragma unroll
        for (int e = 0; e < 8; ++e) {
            float w = (e < 4) ? wa[e] : wb[e - 4];
            float d = (e < 4) ? da[e] : db[e - 4];
            float a = w + SCALING * lor[e];
            if (mk[e]) a += d;
            ov[e] = __float2bfloat16(a);
        }
        *(int4v*)(Weff + base) = ov4;
    } else {
        // ---- convert X ----
        size_t i = ((size_t)(bid - 8192) * 256 + threadIdx.x) * 8;
        f32x4 a = *(const f32x4*)(X + i);
        f32x4 b = *(const f32x4*)(X + i + 4);
        int4v ov4;
        bf16* ov = (bf16*)&ov4;
#pragma unroll
        for (int e = 0; e < 4; ++e) {
            ov[e]     = __float2bfloat16(a[e]);
            ov[e + 4] = __float2bfloat16(b[e]);
        }
        *(int4v*)(Xb + i) = ov4;
    }
}

// ---------------------------------------------------------------------------
// 256x256 8-phase GEMM (bf16 x bf16 -> fp32), m201-style schedule in plain HIP.
// BK=64, 8 waves (2M x 4N), per-wave 128x64 output, acc[8][4] f32x4.
// LDS 128 KB (2 dbuf x (A 32K + B 32K)), 1 block/CU, 2 waves/SIMD.
// Zero-conflict chunk-XOR swizzle (16B chunk ^ (row&7)) applied via
// pre-swizzled GLOBAL source address; LDS dest stays linear (gload_lds rule).
// Counted vmcnt(4) at each tile boundary — never vmcnt(0) in the main loop.
// Raw s_barrier only (no __syncthreads -> no forced vmcnt(0) drain).
//
// Stage schedule per tile t (cur = t&1):
//   P0: ds_read a[0..3],b[0..1] | stage B half0(t+1) -> Bs[cur^1] | mfma (mq0,nq0)
//   P1: ds_read a[4..7]         | stage B half1(t+1) -> Bs[cur^1] | mfma (mq1,nq0)
//   P2: ds_read b[2..3]         | stage A half0(t+2) -> As[cur]   | mfma (mq0,nq1)
//   P3: (no reads)              | stage A half1(t+2) -> As[cur]   | mfma (mq1,nq1)
//       + s_waitcnt vmcnt(4) + barrier
// Safety: A(t+2) overwrites As[cur] only after all A-reads (P0/P1) drained;
// B stages always target the non-read buffer. At each boundary the 4
// outstanding loads are exactly A(t+2) — everything tile t+1 needs has landed.
// ---------------------------------------------------------------------------
__device__ __forceinline__ void stage_half(
    const bf16* __restrict__ g, int grow0, bf16* l, int half, int kt,
    int tid, int wvb)
{
    const int k0 = (kt < NT) ? kt * 64 : 0;   // tail: dummy load into dead region
#pragma unroll
    for (int gi = 0; gi < 2; ++gi) {
        const int c  = gi * 512 + tid;
        const int ml = c >> 3;                 // local row within half (0..127)
        const int kc = (c & 7) ^ (ml & 7);     // pre-swizzled global chunk
        __builtin_amdgcn_global_load_lds(
            (const AS1 void*)(g + (size_t)(grow0 + half * 128 + ml) * KDIM + k0 + kc * 8),
            (AS3 void*)(l + half * 8192 + (gi * 512 + wvb) * 8),
            16, 0, 0);
    }
}

#define RD_A(i) { const int m_ = wm * 128 + (i) * 16 + l16;                       \
    a[i][0] = *(const bf16x8*)(Ac + m_ * 64 + ((quad       ^ (m_ & 7)) * 8));     \
    a[i][1] = *(const bf16x8*)(Ac + m_ * 64 + (((4 + quad) ^ (m_ & 7)) * 8)); }
#define RD_B(j) { const int n_ = wn * 64 + (j) * 16 + l16;                        \
    b[j][0] = *(const bf16x8*)(Bc + n_ * 64 + ((quad       ^ (n_ & 7)) * 8));     \
    b[j][1] = *(const bf16x8*)(Bc + n_ * 64 + (((4 + quad) ^ (n_ & 7)) * 8)); }
#define MF2(i, j)                                                                 \
    acc[i][j] = __builtin_amdgcn_mfma_f32_16x16x32_bf16(a[i][0], b[j][0], acc[i][j], 0, 0, 0); \
    acc[i][j] = __builtin_amdgcn_mfma_f32_16x16x32_bf16(a[i][1], b[j][1], acc[i][j], 0, 0, 0);

__global__ __launch_bounds__(512, 2) void gemm_bf16_256(
    const bf16* __restrict__ X, const bf16* __restrict__ Wt,
    const float* __restrict__ bias, float* __restrict__ out)
{
    __shared__ bf16 As[2][256 * 64];   // 64 KB
    __shared__ bf16 Bs[2][256 * 64];   // 64 KB

    const int tid  = threadIdx.x;
    const int lane = tid & 63;
    const int wvb  = tid & ~63;
    const int wave = tid >> 6;
    const int wm   = wave & 1;         // 2 M-waves
    const int wn   = wave >> 1;        // 4 N-waves
    const int quad = lane >> 4;
    const int l16  = lane & 15;

    // XCD-aware swizzle (512 blocks, 512 % 8 == 0 -> simple form is bijective)
    int idb = blockIdx.y * gridDim.x + blockIdx.x;
    idb = (idb & 7) * 64 + (idb >> 3);
    const int bn = (idb & 15) * 256;   // 16 N-blocks
    const int bm = (idb >> 4) * 256;   // 32 M-blocks

    f32x4 acc[8][4];
#pragma unroll
    for (int i = 0; i < 8; ++i)
#pragma unroll
        for (int j = 0; j < 4; ++j)
            acc[i][j] = (f32x4){0.f, 0.f, 0.f, 0.f};

    // Prologue: A(0), B(0), A(1).  12 loads; force the 8 for tile 0, keep
    // A(1)'s 4 in flight.
    stage_half(X,  bm, As[0], 0, 0, tid, wvb);
    stage_half(X,  bm, As[0], 1, 0, tid, wvb);
    stage_half(Wt, bn, Bs[0], 0, 0, tid, wvb);
    stage_half(Wt, bn, Bs[0], 1, 0, tid, wvb);
    stage_half(X,  bm, As[1], 0, 1, tid, wvb);
    stage_half(X,  bm, As[1], 1, 1, tid, wvb);
    asm volatile("s_waitcnt vmcnt(4)" ::: "memory");
    __builtin_amdgcn_s_barrier();

    bf16x8 a[8][2], b[4][2];

    for (int t = 0; t < NT; ++t) {
        const int cur = t & 1;
        const bf16* Ac = As[cur];
        const bf16* Bc = Bs[cur];

        // ---- P0: quadrant (mq0, nq0) ----
        RD_A(0) RD_A(1) RD_A(2) RD_A(3)
        RD_B(0) RD_B(1)
        stage_half(Wt, bn, Bs[cur ^ 1], 0, t + 1, tid, wvb);
        __builtin_amdgcn_s_barrier();
        __builtin_amdgcn_s_setprio(1);
        MF2(0,0) MF2(1,0) MF2(2,0) MF2(3,0)
        MF2(0,1) MF2(1,1) MF2(2,1) MF2(3,1)
        __builtin_amdgcn_s_setprio(0);
        __builtin_amdgcn_s_barrier();

        // ---- P1: quadrant (mq1, nq0) ----
        RD_A(4) RD_A(5) RD_A(6) RD_A(7)
        stage_half(Wt, bn, Bs[cur ^ 1], 1, t + 1, tid, wvb);
        __builtin_amdgcn_s_barrier();
        __builtin_amdgcn_s_setprio(1);
        MF2(4,0) MF2(5,0) MF2(6,0) MF2(7,0)
        MF2(4,1) MF2(5,1) MF2(6,1) MF2(7,1)
        __builtin_amdgcn_s_setprio(0);
        __builtin_amdgcn_s_barrier();

        // ---- P2: quadrant (mq0, nq1) ----
        RD_B(2) RD_B(3)
        stage_half(X, bm, As[cur], 0, t + 2, tid, wvb);
        __builtin_amdgcn_s_barrier();
        __builtin_amdgcn_s_setprio(1);
        MF2(0,2) MF2(1,2) MF2(2,2) MF2(3,2)
        MF2(0,3) MF2(1,3) MF2(2,3) MF2(3,3)
        __builtin_amdgcn_s_setprio(0);
        __builtin_amdgcn_s_barrier();

        // ---- P3: quadrant (mq1, nq1) ----
        stage_half(X, bm, As[cur], 1, t + 2, tid, wvb);
        __builtin_amdgcn_s_barrier();
        __builtin_amdgcn_s_setprio(1);
        MF2(4,2) MF2(5,2) MF2(6,2) MF2(7,2)
        MF2(4,3) MF2(5,3) MF2(6,3) MF2(7,3)
        __builtin_amdgcn_s_setprio(0);
        asm volatile("s_waitcnt vmcnt(4)" ::: "memory");
        __builtin_amdgcn_s_barrier();
    }

    // Epilogue.  C/D layout: col = lane&15, row = quad*4 + reg.
    float bv[4];
#pragma unroll
    for (int j = 0; j < 4; ++j)
        bv[j] = bias[bn + wn * 64 + j * 16 + l16];

#pragma unroll
    for (int i = 0; i < 8; ++i) {
        const int mg = bm + wm * 128 + i * 16 + quad * 4;
#pragma unroll
        for (int j = 0; j < 4; ++j) {
            const int ng = bn + wn * 64 + j * 16 + l16;
#pragma unroll
            for (int r = 0; r < 4; ++r)
                out[(size_t)(mg + r) * NDIM + ng] = acc[i][j][r] + bv[j];
        }
    }
}

// ---------------------------------------------------------------------------
// Fallback GEMM (fp32 X staged as f32 in LDS) — used only if ws_size can't
// fit the bf16 copy of X.  Unchanged from the proven version.
// ---------------------------------------------------------------------------
__global__ __launch_bounds__(256, 3) void gemm_f32(
    const float* __restrict__ X, const bf16* __restrict__ Wt,
    const float* __restrict__ bias, float* __restrict__ out)
{
    __shared__ float Asf[128 * 64];  // 32 KB
    __shared__ bf16  Bs[128 * 64];   // 16 KB

    const int tid  = threadIdx.x;
    const int lane = tid & 63;
    const int wave = tid >> 6;
    const int wmf  = wave & 1;
    const int wnf  = wave >> 1;
    const int quad = lane >> 4;
    const int l16  = lane & 15;

    const int bn = blockIdx.x * 128;
    const int bm = blockIdx.y * 128;
    const int cwave = tid & ~63;

    f32x4 acc[4][4];
#pragma unroll
    for (int i = 0; i < 4; ++i)
#pragma unroll
        for (int j = 0; j < 4; ++j)
            acc[i][j] = (f32x4){0.f, 0.f, 0.f, 0.f};

    for (int kt = 0; kt < KDIM / 64; ++kt) {
        const int k0 = kt * 64;
        if (kt) __syncthreads();
#pragma unroll
        for (int j = 0; j < 8; ++j) {
            const int c  = j * 256 + tid;
            const int m  = c >> 4;
            const int kc = (c & 15) ^ (m & 15);
            const int cb = j * 256 + cwave;
            __builtin_amdgcn_global_load_lds(
                (const AS1 void*)(X + (size_t)(bm + m) * KDIM + k0 + kc * 4),
                (AS3 void*)(Asf + cb * 4), 16, 0, 0);
        }
#pragma unroll
        for (int j = 0; j < 4; ++j) {
            const int c  = j * 256 + tid;
            const int m  = c >> 3;
            const int kc = (c & 7) ^ (m & 7);
            const int cb = j * 256 + cwave;
            __builtin_amdgcn_global_load_lds(
                (const AS1 void*)(Wt + (size_t)(bn + m) * KDIM + k0 + kc * 8),
                (AS3 void*)(Bs + cb * 8), 16, 0, 0);
        }
        __syncthreads();

#pragma unroll
        for (int ks = 0; ks < 2; ++ks) {
            bf16x8 af[4], bfr[4];
#pragma unroll
            for (int i = 0; i < 4; ++i) {
                const int m  = wmf * 64 + i * 16 + l16;
                const int k2 = (ks * 4 + quad) * 2;
                f32x4 lo = *(const f32x4*)(Asf + m * 64 + ((k2     ^ (m & 15)) * 4));
                f32x4 hi = *(const f32x4*)(Asf + m * 64 + (((k2+1) ^ (m & 15)) * 4));
                bf16 tmp[8];
#pragma unroll
                for (int e = 0; e < 4; ++e) {
                    tmp[e]     = __float2bfloat16(lo[e]);
                    tmp[e + 4] = __float2bfloat16(hi[e]);
                }
                af[i] = *(const bf16x8*)tmp;

                const int n   = wnf * 64 + i * 16 + l16;
                const int kcb = (ks * 4 + quad) ^ (n & 7);
                bfr[i] = *(const bf16x8*)(Bs + n * 64 + kcb * 8);
            }
#pragma unroll
            for (int i = 0; i < 4; ++i)
#pragma unroll
                for (int j = 0; j < 4; ++j)
                    acc[i][j] = __builtin_amdgcn_mfma_f32_16x16x32_bf16(
                        af[i], bfr[j], acc[i][j], 0, 0, 0);
        }
    }

    float bv[4];
#pragma unroll
    for (int j = 0; j < 4; ++j)
        bv[j] = bias[bn + wnf * 64 + j * 16 + l16];

#pragma unroll
    for (int i = 0; i < 4; ++i) {
        const int mg = bm + wmf * 64 + i * 16 + quad * 4;
#pragma unroll
        for (int j = 0; j < 4; ++j) {
            const int ng = bn + wnf * 64 + j * 16 + l16;
#pragma unroll
            for (int r = 0; r < 4; ++r)
                out[(size_t)(mg + r) * NDIM + ng] = acc[i][j][r] + bv[j];
        }
    }
}

// ---------------------------------------------------------------------------
extern "C" void kernel_launch(void* const* d_in, const int* in_sizes, int n_in,
                              void* d_out, int out_size, void* d_ws, size_t ws_size,
                              hipStream_t stream)
{
    const float* x     = (const float*)d_in[0];
    const float* W     = (const float*)d_in[1];
    const float* b     = (const float*)d_in[2];
    const float* lA    = (const float*)d_in[3];
    const float* lB    = (const float*)d_in[4];
    const float* delta = (const float*)d_in[5];
    const int*   mask  = (const int*)d_in[6];
    float* out = (float*)d_out;

    bf16* Weff = (bf16*)d_ws;                                     // 33.5 MB
    bf16* Xb   = (bf16*)((char*)d_ws + (size_t)NDIM * KDIM * 2);  // 67 MB

    const size_t need = (size_t)NDIM * KDIM * 2 + (size_t)MDIM * KDIM * 2;

    if (ws_size >= need) {
        prep<<<dim3(8192 + 16384), 256, 0, stream>>>(
            W, lA, lB, delta, mask, Weff, x, Xb);
        gemm_bf16_256<<<dim3(NDIM / 256, MDIM / 256), 512, 0, stream>>>(
            Xb, Weff, b, out);
    } else {
        prep<<<dim3(8192), 256, 0, stream>>>(
            W, lA, lB, delta, mask, Weff, x, Xb);
        gemm_f32<<<dim3(NDIM / 128, MDIM / 128), 256, 0, stream>>>(
            x, Weff, b, out);
    }
}

// Round 2
// 667.141 us; speedup vs baseline: 1.0162x; 1.0162x over previous
//
#include <hip/hip_runtime.h>
#include <hip/hip_bf16.h>

typedef __hip_bfloat16 bf16;
typedef __attribute__((ext_vector_type(8))) short bf16x8;   // 8 bf16 = 4 VGPRs
typedef __attribute__((ext_vector_type(4))) float f32x4;
typedef __attribute__((ext_vector_type(4))) int int4v;

#define AS1 __attribute__((address_space(1)))
#define AS3 __attribute__((address_space(3)))

#define MDIM 8192   // B*S
#define NDIM 4096   // D_OUT
#define KDIM 4096   // D_IN
#define SCALING 2.0f
#define NT (KDIM / 64)   // 64 K-tiles of BK=64

// ---------------------------------------------------------------------------
// prep: fused fold (Weff = W + s*B@A + mask?delta) + X fp32->bf16 convert.
// ---------------------------------------------------------------------------
__global__ __launch_bounds__(256) void prep(
    const float* __restrict__ W, const float* __restrict__ lA,
    const float* __restrict__ lB, const float* __restrict__ delta,
    const int* __restrict__ mask, bf16* __restrict__ Weff,
    const float* __restrict__ X, bf16* __restrict__ Xb)
{
    const int bid = blockIdx.x;
    if (bid < 8192) {
        int idx = bid * 256 + threadIdx.x;
        int o   = idx >> 9;
        int d0  = (idx & 511) << 3;
        size_t base = (size_t)o * KDIM + d0;

        float Bo[16];
#pragma unroll
        for (int r = 0; r < 16; ++r) Bo[r] = lB[o * 16 + r];

        f32x4 wa = *(const f32x4*)(W + base);
        f32x4 wb = *(const f32x4*)(W + base + 4);
        f32x4 da = *(const f32x4*)(delta + base);
        f32x4 db = *(const f32x4*)(delta + base + 4);

        int mk[8];
        *(int4v*)(mk)     = *(const int4v*)(mask + base);
        *(int4v*)(mk + 4) = *(const int4v*)(mask + base + 4);

        float lor[8] = {0.f, 0.f, 0.f, 0.f, 0.f, 0.f, 0.f, 0.f};
#pragma unroll
        for (int r = 0; r < 16; ++r) {
            f32x4 aa = *(const f32x4*)(lA + (size_t)r * KDIM + d0);
            f32x4 ab = *(const f32x4*)(lA + (size_t)r * KDIM + d0 + 4);
#pragma unroll
            for (int e = 0; e < 4; ++e) {
                lor[e]     += Bo[r] * aa[e];
                lor[e + 4] += Bo[r] * ab[e];
            }
        }

        int4v ov4;
        bf16* ov = (bf16*)&ov4;
#pragma unroll
        for (int e = 0; e < 8; ++e) {
            float w = (e < 4) ? wa[e] : wb[e - 4];
            float d = (e < 4) ? da[e] : db[e - 4];
            float a = w + SCALING * lor[e];
            if (mk[e]) a += d;
            ov[e] = __float2bfloat16(a);
        }
        *(int4v*)(Weff + base) = ov4;
    } else {
        size_t i = ((size_t)(bid - 8192) * 256 + threadIdx.x) * 8;
        f32x4 a = *(const f32x4*)(X + i);
        f32x4 b = *(const f32x4*)(X + i + 4);
        int4v ov4;
        bf16* ov = (bf16*)&ov4;
#pragma unroll
        for (int e = 0; e < 4; ++e) {
            ov[e]     = __float2bfloat16(a[e]);
            ov[e + 4] = __float2bfloat16(b[e]);
        }
        *(int4v*)(Xb + i) = ov4;
    }
}

// ---------------------------------------------------------------------------
// 256x256 pipelined GEMM, phases by (m-half, k-half), ds_reads ONE PHASE
// AHEAD so compiler's counted lgkmcnt leaves them in flight under MFMA:
//   P0: rd{aK0[4-7],aK1[0-3]} | stage B(t+1)h0 | M0 = (i0-3, k0)  16 MFMA
//   P1: rd{bK1, aK1[4-7]}     | stage B(t+1)h1 | M1 = (i4-7, k0)
//   P2: (no reads)            | stage A(t+2)h0+h1 -> As[cur] | M2 = (i0-3, k1)
//   P3: vmcnt(4) + barrier; rd next-tile{aK0[0-3],bK0} from As/Bs[cur^1] | M3
// Safety: all As[cur] reads issued by end of P1 => A(t+2) staging into
// As[cur] at P2 is the round-1-proven pattern. P3's next-buffer reads come
// after EVERY wave's vmcnt(4) + a barrier (per-wave vmcnt alone is not
// cross-wave visibility). vmcnt never drains to 0 in the loop (A(t+2) flies
// across the boundary). Compile-time memory fences pin phase membership.
// ---------------------------------------------------------------------------
__device__ __forceinline__ void stage_half(
    const bf16* __restrict__ g, int grow0, bf16* l, int half, int kt,
    int tid, int wvb)
{
    const int k0 = (kt < NT) ? kt * 64 : 0;   // tail: dummy load, keeps vmcnt math
#pragma unroll
    for (int gi = 0; gi < 2; ++gi) {
        const int c  = gi * 512 + tid;
        const int ml = c >> 3;
        const int kc = (c & 7) ^ (ml & 7);     // pre-swizzled global chunk
        __builtin_amdgcn_global_load_lds(
            (const AS1 void*)(g + (size_t)(grow0 + half * 128 + ml) * KDIM + k0 + kc * 8),
            (AS3 void*)(l + half * 8192 + (gi * 512 + wvb) * 8),
            16, 0, 0);
    }
}

#define FENCE asm volatile("" ::: "memory")

#define RD_A(arr, i, ks, P) { const int m_ = wm * 128 + (i) * 16 + l16;           \
    arr[i] = *(const bf16x8*)((P) + m_ * 64 + ((((ks) * 4 + quad) ^ (m_ & 7)) * 8)); }
#define RD_B(arr, j, ks, P) { const int n_ = wn * 64 + (j) * 16 + l16;            \
    arr[j] = *(const bf16x8*)((P) + n_ * 64 + ((((ks) * 4 + quad) ^ (n_ & 7)) * 8)); }

__global__ __launch_bounds__(512, 2) void gemm_bf16_256(
    const bf16* __restrict__ X, const bf16* __restrict__ Wt,
    const float* __restrict__ bias, float* __restrict__ out)
{
    __shared__ bf16 As[2][256 * 64];   // 64 KB
    __shared__ bf16 Bs[2][256 * 64];   // 64 KB

    const int tid  = threadIdx.x;
    const int lane = tid & 63;
    const int wvb  = tid & ~63;
    const int wave = tid >> 6;
    const int wm   = wave & 1;         // 2 M-waves
    const int wn   = wave >> 1;        // 4 N-waves
    const int quad = lane >> 4;
    const int l16  = lane & 15;

    // XCD-aware swizzle (512 blocks, 512 % 8 == 0 -> bijective)
    int idb = blockIdx.y * gridDim.x + blockIdx.x;
    idb = (idb & 7) * 64 + (idb >> 3);
    const int bn = (idb & 15) * 256;
    const int bm = (idb >> 4) * 256;

    f32x4 acc[8][4];
#pragma unroll
    for (int i = 0; i < 8; ++i)
#pragma unroll
        for (int j = 0; j < 4; ++j)
            acc[i][j] = (f32x4){0.f, 0.f, 0.f, 0.f};

    // Prologue: A(0), B(0), A(1) staged; drain A(0)+B(0), keep A(1) flying.
    stage_half(X,  bm, As[0], 0, 0, tid, wvb);
    stage_half(X,  bm, As[0], 1, 0, tid, wvb);
    stage_half(Wt, bn, Bs[0], 0, 0, tid, wvb);
    stage_half(Wt, bn, Bs[0], 1, 0, tid, wvb);
    stage_half(X,  bm, As[1], 0, 1, tid, wvb);
    stage_half(X,  bm, As[1], 1, 1, tid, wvb);
    asm volatile("s_waitcnt vmcnt(4)" ::: "memory");
    __builtin_amdgcn_s_barrier();
    FENCE;

    bf16x8 aK0[8], aK1[8], bK0[4], bK1[4];

    // First G0: fragments for tile 0's M0.
#pragma unroll
    for (int i = 0; i < 4; ++i) RD_A(aK0, i, 0, As[0]);
#pragma unroll
    for (int j = 0; j < 4; ++j) RD_B(bK0, j, 0, Bs[0]);

    for (int t = 0; t < NT; ++t) {
        const int cur = t & 1;
        const bf16* Ac = As[cur];
        const bf16* Bc = Bs[cur];
        const bf16* An = As[cur ^ 1];
        const bf16* Bn = Bs[cur ^ 1];

        // ---- P0 ----
#pragma unroll
        for (int i = 4; i < 8; ++i) RD_A(aK0, i, 0, Ac);
#pragma unroll
        for (int i = 0; i < 4; ++i) RD_A(aK1, i, 1, Ac);
        stage_half(Wt, bn, Bs[cur ^ 1], 0, t + 1, tid, wvb);
        FENCE;
        __builtin_amdgcn_s_barrier();
        __builtin_amdgcn_s_setprio(1);
#pragma unroll
        for (int i = 0; i < 4; ++i)
#pragma unroll
            for (int j = 0; j < 4; ++j)
                acc[i][j] = __builtin_amdgcn_mfma_f32_16x16x32_bf16(
                    aK0[i], bK0[j], acc[i][j], 0, 0, 0);
        __builtin_amdgcn_s_setprio(0);
        FENCE;
        __builtin_amdgcn_s_barrier();

        // ---- P1 ----
#pragma unroll
        for (int j = 0; j < 4; ++j) RD_B(bK1, j, 1, Bc);
#pragma unroll
        for (int i = 4; i < 8; ++i) RD_A(aK1, i, 1, Ac);
        stage_half(Wt, bn, Bs[cur ^ 1], 1, t + 1, tid, wvb);
        FENCE;
        __builtin_amdgcn_s_barrier();
        __builtin_amdgcn_s_setprio(1);
#pragma unroll
        for (int i = 4; i < 8; ++i)
#pragma unroll
            for (int j = 0; j < 4; ++j)
                acc[i][j] = __builtin_amdgcn_mfma_f32_16x16x32_bf16(
                    aK0[i], bK0[j], acc[i][j], 0, 0, 0);
        __builtin_amdgcn_s_setprio(0);
        FENCE;
        __builtin_amdgcn_s_barrier();

        // ---- P2 ----
        stage_half(X, bm, As[cur], 0, t + 2, tid, wvb);
        stage_half(X, bm, As[cur], 1, t + 2, tid, wvb);
        FENCE;
        __builtin_amdgcn_s_barrier();
        __builtin_amdgcn_s_setprio(1);
#pragma unroll
        for (int i = 0; i < 4; ++i)
#pragma unroll
            for (int j = 0; j < 4; ++j)
                acc[i][j] = __builtin_amdgcn_mfma_f32_16x16x32_bf16(
                    aK1[i], bK1[j], acc[i][j], 0, 0, 0);
        __builtin_amdgcn_s_setprio(0);
        FENCE;
        __builtin_amdgcn_s_barrier();

        // ---- P3 ----
        asm volatile("s_waitcnt vmcnt(4)" ::: "memory");  // A(t+1),B(t+1) landed
        __builtin_amdgcn_s_barrier();                      // ...for ALL waves
        FENCE;
#pragma unroll
        for (int i = 0; i < 4; ++i) RD_A(aK0, i, 0, An);   // next tile's G0,
#pragma unroll
        for (int j = 0; j < 4; ++j) RD_B(bK0, j, 0, Bn);   // flies under M3
        __builtin_amdgcn_s_setprio(1);
#pragma unroll
        for (int i = 4; i < 8; ++i)
#pragma unroll
            for (int j = 0; j < 4; ++j)
                acc[i][j] = __builtin_amdgcn_mfma_f32_16x16x32_bf16(
                    aK1[i], bK1[j], acc[i][j], 0, 0, 0);
        __builtin_amdgcn_s_setprio(0);
        FENCE;
        __builtin_amdgcn_s_barrier();
    }

    // Epilogue.  C/D layout: col = lane&15, row = quad*4 + reg.
    float bv[4];
#pragma unroll
    for (int j = 0; j < 4; ++j)
        bv[j] = bias[bn + wn * 64 + j * 16 + l16];

#pragma unroll
    for (int i = 0; i < 8; ++i) {
        const int mg = bm + wm * 128 + i * 16 + quad * 4;
#pragma unroll
        for (int j = 0; j < 4; ++j) {
            const int ng = bn + wn * 64 + j * 16 + l16;
#pragma unroll
            for (int r = 0; r < 4; ++r)
                out[(size_t)(mg + r) * NDIM + ng] = acc[i][j][r] + bv[j];
        }
    }
}

// ---------------------------------------------------------------------------
// Fallback GEMM (fp32 X) — used only if ws can't fit the bf16 copy of X.
// ---------------------------------------------------------------------------
__global__ __launch_bounds__(256, 3) void gemm_f32(
    const float* __restrict__ X, const bf16* __restrict__ Wt,
    const float* __restrict__ bias, float* __restrict__ out)
{
    __shared__ float Asf[128 * 64];  // 32 KB
    __shared__ bf16  Bs[128 * 64];   // 16 KB

    const int tid  = threadIdx.x;
    const int lane = tid & 63;
    const int wave = tid >> 6;
    const int wmf  = wave & 1;
    const int wnf  = wave >> 1;
    const int quad = lane >> 4;
    const int l16  = lane & 15;

    const int bn = blockIdx.x * 128;
    const int bm = blockIdx.y * 128;
    const int cwave = tid & ~63;

    f32x4 acc[4][4];
#pragma unroll
    for (int i = 0; i < 4; ++i)
#pragma unroll
        for (int j = 0; j < 4; ++j)
            acc[i][j] = (f32x4){0.f, 0.f, 0.f, 0.f};

    for (int kt = 0; kt < KDIM / 64; ++kt) {
        const int k0 = kt * 64;
        if (kt) __syncthreads();
#pragma unroll
        for (int j = 0; j < 8; ++j) {
            const int c  = j * 256 + tid;
            const int m  = c >> 4;
            const int kc = (c & 15) ^ (m & 15);
            const int cb = j * 256 + cwave;
            __builtin_amdgcn_global_load_lds(
                (const AS1 void*)(X + (size_t)(bm + m) * KDIM + k0 + kc * 4),
                (AS3 void*)(Asf + cb * 4), 16, 0, 0);
        }
#pragma unroll
        for (int j = 0; j < 4; ++j) {
            const int c  = j * 256 + tid;
            const int m  = c >> 3;
            const int kc = (c & 7) ^ (m & 7);
            const int cb = j * 256 + cwave;
            __builtin_amdgcn_global_load_lds(
                (const AS1 void*)(Wt + (size_t)(bn + m) * KDIM + k0 + kc * 8),
                (AS3 void*)(Bs + cb * 8), 16, 0, 0);
        }
        __syncthreads();

#pragma unroll
        for (int ks = 0; ks < 2; ++ks) {
            bf16x8 af[4], bfr[4];
#pragma unroll
            for (int i = 0; i < 4; ++i) {
                const int m  = wmf * 64 + i * 16 + l16;
                const int k2 = (ks * 4 + quad) * 2;
                f32x4 lo = *(const f32x4*)(Asf + m * 64 + ((k2     ^ (m & 15)) * 4));
                f32x4 hi = *(const f32x4*)(Asf + m * 64 + (((k2+1) ^ (m & 15)) * 4));
                bf16 tmp[8];
#pragma unroll
                for (int e = 0; e < 4; ++e) {
                    tmp[e]     = __float2bfloat16(lo[e]);
                    tmp[e + 4] = __float2bfloat16(hi[e]);
                }
                af[i] = *(const bf16x8*)tmp;

                const int n   = wnf * 64 + i * 16 + l16;
                const int kcb = (ks * 4 + quad) ^ (n & 7);
                bfr[i] = *(const bf16x8*)(Bs + n * 64 + kcb * 8);
            }
#pragma unroll
            for (int i = 0; i < 4; ++i)
#pragma unroll
                for (int j = 0; j < 4; ++j)
                    acc[i][j] = __builtin_amdgcn_mfma_f32_16x16x32_bf16(
                        af[i], bfr[j], acc[i][j], 0, 0, 0);
        }
    }

    float bv[4];
#pragma unroll
    for (int j = 0; j < 4; ++j)
        bv[j] = bias[bn + wnf * 64 + j * 16 + l16];

#pragma unroll
    for (int i = 0; i < 4; ++i) {
        const int mg = bm + wmf * 64 + i * 16 + quad * 4;
#pragma unroll
        for (int j = 0; j < 4; ++j) {
            const int ng = bn + wnf * 64 + j * 16 + l16;
#pragma unroll
            for (int r = 0; r < 4; ++r)
                out[(size_t)(mg + r) * NDIM + ng] = acc[i][j][r] + bv[j];
        }
    }
}

// ---------------------------------------------------------------------------
extern "C" void kernel_launch(void* const* d_in, const int* in_sizes, int n_in,
                              void* d_out, int out_size, void* d_ws, size_t ws_size,
                              hipStream_t stream)
{
    const float* x     = (const float*)d_in[0];
    const float* W     = (const float*)d_in[1];
    const float* b     = (const float*)d_in[2];
    const float* lA    = (const float*)d_in[3];
    const float* lB    = (const float*)d_in[4];
    const float* delta = (const float*)d_in[5];
    const int*   mask  = (const int*)d_in[6];
    float* out = (float*)d_out;

    bf16* Weff = (bf16*)d_ws;                                     // 33.5 MB
    bf16* Xb   = (bf16*)((char*)d_ws + (size_t)NDIM * KDIM * 2);  // 67 MB

    const size_t need = (size_t)NDIM * KDIM * 2 + (size_t)MDIM * KDIM * 2;

    if (ws_size >= need) {
        prep<<<dim3(8192 + 16384), 256, 0, stream>>>(
            W, lA, lB, delta, mask, Weff, x, Xb);
        gemm_bf16_256<<<dim3(NDIM / 256, MDIM / 256), 512, 0, stream>>>(
            Xb, Weff, b, out);
    } else {
        prep<<<dim3(8192), 256, 0, stream>>>(
            W, lA, lB, delta, mask, Weff, x, Xb);
        gemm_f32<<<dim3(NDIM / 128, MDIM / 128), 256, 0, stream>>>(
            x, Weff, b, out);
    }
}

// Round 3
// 666.254 us; speedup vs baseline: 1.0176x; 1.0013x over previous
//
#include <hip/hip_runtime.h>
#include <hip/hip_bf16.h>

typedef __hip_bfloat16 bf16;
typedef __attribute__((ext_vector_type(8))) short bf16x8;   // 8 bf16 = 4 VGPRs
typedef __attribute__((ext_vector_type(4))) float f32x4;
typedef __attribute__((ext_vector_type(4))) int int4v;

#define AS1 __attribute__((address_space(1)))
#define AS3 __attribute__((address_space(3)))

#define MDIM 8192   // B*S
#define NDIM 4096   // D_OUT
#define KDIM 4096   // D_IN
#define SCALING 2.0f

// ---------------------------------------------------------------------------
// prep: fused fold + convert.
//   Blocks [0, 2048):    fold Weff = W + s*(lB@lA) + mask?delta  (bf16 out)
//                        each block = 16 o-rows x 512 d-cols; lA tile (16x512,
//                        32 KB) staged in LDS once per block -> kills the ~1 GB
//                        of per-thread lA re-reads from L2.  One wave = one
//                        contiguous 512-float row-slice: perfectly coalesced
//                        loads/stores, wave-uniform o -> lB reads are scalar.
//   Blocks [2048, 4096): grid-stride X fp32 -> bf16 convert.
// ---------------------------------------------------------------------------
__global__ __launch_bounds__(256) void prep(
    const float* __restrict__ W, const float* __restrict__ lA,
    const float* __restrict__ lB, const float* __restrict__ delta,
    const int* __restrict__ mask, bf16* __restrict__ Weff,
    const float* __restrict__ X, bf16* __restrict__ Xb)
{
    __shared__ float sA[16 * 512];   // 32 KB -> 5 blocks/CU
    const int bid = blockIdx.x;
    const int tid = threadIdx.x;

    if (bid < 2048) {
        // ---- fold ----
        const int ob = (bid >> 3) * 16;     // o-tile base (256 tiles)
        const int db = (bid & 7) * 512;     // d-tile base (8 tiles)

        // stage lA[0..16)[db..db+512) into LDS (2048 f32x4 loads)
#pragma unroll
        for (int i = tid; i < 2048; i += 256) {
            const int row = i >> 7;          // 0..15
            const int qc  = (i & 127) * 4;   // 0..508
            *(f32x4*)(sA + row * 512 + qc) =
                *(const f32x4*)(lA + (size_t)row * KDIM + db + qc);
        }
        __syncthreads();

        // 1024 chunks of 8 outputs; wave = one row-slice of 512 floats
        for (int c = tid; c < 1024; c += 256) {
            const int o_l = c >> 6;              // 0..15 (wave-uniform)
            const int dc  = (c & 63) * 8;        // 0..504
            const int o   = ob + o_l;
            const size_t base = (size_t)o * KDIM + db + dc;

            float Bo[16];
#pragma unroll
            for (int r = 0; r < 16; ++r) Bo[r] = lB[o * 16 + r];

            f32x4 wa = *(const f32x4*)(W + base);
            f32x4 wb = *(const f32x4*)(W + base + 4);
            f32x4 da = *(const f32x4*)(delta + base);
            f32x4 db4 = *(const f32x4*)(delta + base + 4);

            int mk[8];
            *(int4v*)(mk)     = *(const int4v*)(mask + base);
            *(int4v*)(mk + 4) = *(const int4v*)(mask + base + 4);

            float lor[8] = {0.f, 0.f, 0.f, 0.f, 0.f, 0.f, 0.f, 0.f};
#pragma unroll
            for (int r = 0; r < 16; ++r) {
                f32x4 aa = *(const f32x4*)(sA + r * 512 + dc);
                f32x4 ab = *(const f32x4*)(sA + r * 512 + dc + 4);
#pragma unroll
                for (int e = 0; e < 4; ++e) {
                    lor[e]     += Bo[r] * aa[e];
                    lor[e + 4] += Bo[r] * ab[e];
                }
            }

            int4v ov4;
            bf16* ov = (bf16*)&ov4;
#pragma unroll
            for (int e = 0; e < 8; ++e) {
                float w = (e < 4) ? wa[e] : wb[e - 4];
                float d = (e < 4) ? da[e] : db4[e - 4];
                float a = w + SCALING * lor[e];
                if (mk[e]) a += d;
                ov[e] = __float2bfloat16(a);
            }
            *(int4v*)(Weff + base) = ov4;
        }
    } else {
        // ---- convert X (grid-stride, 8 iters/thread) ----
        const size_t nchunk = (size_t)MDIM * KDIM / 8;   // 4,194,304
        for (size_t c = (size_t)(bid - 2048) * 256 + tid; c < nchunk;
             c += (size_t)2048 * 256) {
            const size_t i = c * 8;
            f32x4 a = *(const f32x4*)(X + i);
            f32x4 b = *(const f32x4*)(X + i + 4);
            int4v ov4;
            bf16* ov = (bf16*)&ov4;
#pragma unroll
            for (int e = 0; e < 4; ++e) {
                ov[e]     = __float2bfloat16(a[e]);
                ov[e + 4] = __float2bfloat16(b[e]);
            }
            *(int4v*)(Xb + i) = ov4;
        }
    }
}

// ---------------------------------------------------------------------------
// GEMM (bf16 x bf16 -> fp32) — the proven round-0 m97-structure kernel
// (272 us, MfmaUtil 48.6, 0 bank conflicts), plus bijective XCD swizzle
// (2048 blocks, 2048 % 8 == 0) for cross-block L2 locality.
// 128x128 tile, BK=64, 2x2 waves, 4x4 mfma_f32_16x16x32_bf16.
// ---------------------------------------------------------------------------
__global__ __launch_bounds__(256, 4) void gemm_bf16(
    const bf16* __restrict__ X, const bf16* __restrict__ Wt,
    const float* __restrict__ bias, float* __restrict__ out)
{
    __shared__ bf16 As[128 * 64];   // 16 KB
    __shared__ bf16 Bs[128 * 64];   // 16 KB

    const int tid  = threadIdx.x;
    const int lane = tid & 63;
    const int wave = tid >> 6;
    const int wm   = wave & 1;
    const int wn   = wave >> 1;
    const int quad = lane >> 4;
    const int l16  = lane & 15;

    // XCD-aware bijective swizzle: 2048 blocks -> 8 chunks of 256
    int flat = blockIdx.y * gridDim.x + blockIdx.x;
    flat = (flat & 7) * 256 + (flat >> 3);
    const int bn = (flat & 31) * 128;    // 32 n-blocks
    const int bm = (flat >> 5) * 128;    // 64 m-blocks
    const int cwave = tid & ~63;

    f32x4 acc[4][4];
#pragma unroll
    for (int i = 0; i < 4; ++i)
#pragma unroll
        for (int j = 0; j < 4; ++j)
            acc[i][j] = (f32x4){0.f, 0.f, 0.f, 0.f};

    for (int kt = 0; kt < KDIM / 64; ++kt) {
        const int k0 = kt * 64;
        if (kt) __syncthreads();
#pragma unroll
        for (int j = 0; j < 4; ++j) {
            const int c  = j * 256 + tid;
            const int m  = c >> 3;
            const int kc = (c & 7) ^ (m & 7);
            const int cb = j * 256 + cwave;
            __builtin_amdgcn_global_load_lds(
                (const AS1 void*)(X + (size_t)(bm + m) * KDIM + k0 + kc * 8),
                (AS3 void*)(As + cb * 8), 16, 0, 0);
            __builtin_amdgcn_global_load_lds(
                (const AS1 void*)(Wt + (size_t)(bn + m) * KDIM + k0 + kc * 8),
                (AS3 void*)(Bs + cb * 8), 16, 0, 0);
        }
        __syncthreads();

#pragma unroll
        for (int ks = 0; ks < 2; ++ks) {
            bf16x8 af[4], bfr[4];
#pragma unroll
            for (int i = 0; i < 4; ++i) {
                const int m   = wm * 64 + i * 16 + l16;
                const int kca = (ks * 4 + quad) ^ (m & 7);
                af[i] = *(const bf16x8*)(As + m * 64 + kca * 8);
                const int n   = wn * 64 + i * 16 + l16;
                const int kcb = (ks * 4 + quad) ^ (n & 7);
                bfr[i] = *(const bf16x8*)(Bs + n * 64 + kcb * 8);
            }
#pragma unroll
            for (int i = 0; i < 4; ++i)
#pragma unroll
                for (int j = 0; j < 4; ++j)
                    acc[i][j] = __builtin_amdgcn_mfma_f32_16x16x32_bf16(
                        af[i], bfr[j], acc[i][j], 0, 0, 0);
        }
    }

    // C/D layout: col = lane&15, row = quad*4 + reg
    float bv[4];
#pragma unroll
    for (int j = 0; j < 4; ++j)
        bv[j] = bias[bn + wn * 64 + j * 16 + l16];

#pragma unroll
    for (int i = 0; i < 4; ++i) {
        const int mg = bm + wm * 64 + i * 16 + quad * 4;
#pragma unroll
        for (int j = 0; j < 4; ++j) {
            const int ng = bn + wn * 64 + j * 16 + l16;
#pragma unroll
            for (int r = 0; r < 4; ++r)
                out[(size_t)(mg + r) * NDIM + ng] = acc[i][j][r] + bv[j];
        }
    }
}

// ---------------------------------------------------------------------------
// Fallback GEMM (fp32 X) — used only if ws can't fit the bf16 copy of X.
// ---------------------------------------------------------------------------
__global__ __launch_bounds__(256, 3) void gemm_f32(
    const float* __restrict__ X, const bf16* __restrict__ Wt,
    const float* __restrict__ bias, float* __restrict__ out)
{
    __shared__ float Asf[128 * 64];  // 32 KB
    __shared__ bf16  Bs[128 * 64];   // 16 KB

    const int tid  = threadIdx.x;
    const int lane = tid & 63;
    const int wave = tid >> 6;
    const int wmf  = wave & 1;
    const int wnf  = wave >> 1;
    const int quad = lane >> 4;
    const int l16  = lane & 15;

    const int bn = blockIdx.x * 128;
    const int bm = blockIdx.y * 128;
    const int cwave = tid & ~63;

    f32x4 acc[4][4];
#pragma unroll
    for (int i = 0; i < 4; ++i)
#pragma unroll
        for (int j = 0; j < 4; ++j)
            acc[i][j] = (f32x4){0.f, 0.f, 0.f, 0.f};

    for (int kt = 0; kt < KDIM / 64; ++kt) {
        const int k0 = kt * 64;
        if (kt) __syncthreads();
#pragma unroll
        for (int j = 0; j < 8; ++j) {
            const int c  = j * 256 + tid;
            const int m  = c >> 4;
            const int kc = (c & 15) ^ (m & 15);
            const int cb = j * 256 + cwave;
            __builtin_amdgcn_global_load_lds(
                (const AS1 void*)(X + (size_t)(bm + m) * KDIM + k0 + kc * 4),
                (AS3 void*)(Asf + cb * 4), 16, 0, 0);
        }
#pragma unroll
        for (int j = 0; j < 4; ++j) {
            const int c  = j * 256 + tid;
            const int m  = c >> 3;
            const int kc = (c & 7) ^ (m & 7);
            const int cb = j * 256 + cwave;
            __builtin_amdgcn_global_load_lds(
                (const AS1 void*)(Wt + (size_t)(bn + m) * KDIM + k0 + kc * 8),
                (AS3 void*)(Bs + cb * 8), 16, 0, 0);
        }
        __syncthreads();

#pragma unroll
        for (int ks = 0; ks < 2; ++ks) {
            bf16x8 af[4], bfr[4];
#pragma unroll
            for (int i = 0; i < 4; ++i) {
                const int m  = wmf * 64 + i * 16 + l16;
                const int k2 = (ks * 4 + quad) * 2;
                f32x4 lo = *(const f32x4*)(Asf + m * 64 + ((k2     ^ (m & 15)) * 4));
                f32x4 hi = *(const f32x4*)(Asf + m * 64 + (((k2+1) ^ (m & 15)) * 4));
                bf16 tmp[8];
#pragma unroll
                for (int e = 0; e < 4; ++e) {
                    tmp[e]     = __float2bfloat16(lo[e]);
                    tmp[e + 4] = __float2bfloat16(hi[e]);
                }
                af[i] = *(const bf16x8*)tmp;

                const int n   = wnf * 64 + i * 16 + l16;
                const int kcb = (ks * 4 + quad) ^ (n & 7);
                bfr[i] = *(const bf16x8*)(Bs + n * 64 + kcb * 8);
            }
#pragma unroll
            for (int i = 0; i < 4; ++i)
#pragma unroll
                for (int j = 0; j < 4; ++j)
                    acc[i][j] = __builtin_amdgcn_mfma_f32_16x16x32_bf16(
                        af[i], bfr[j], acc[i][j], 0, 0, 0);
        }
    }

    float bv[4];
#pragma unroll
    for (int j = 0; j < 4; ++j)
        bv[j] = bias[bn + wnf * 64 + j * 16 + l16];

#pragma unroll
    for (int i = 0; i < 4; ++i) {
        const int mg = bm + wmf * 64 + i * 16 + quad * 4;
#pragma unroll
        for (int j = 0; j < 4; ++j) {
            const int ng = bn + wnf * 64 + j * 16 + l16;
#pragma unroll
            for (int r = 0; r < 4; ++r)
                out[(size_t)(mg + r) * NDIM + ng] = acc[i][j][r] + bv[j];
        }
    }
}

// ---------------------------------------------------------------------------
extern "C" void kernel_launch(void* const* d_in, const int* in_sizes, int n_in,
                              void* d_out, int out_size, void* d_ws, size_t ws_size,
                              hipStream_t stream)
{
    const float* x     = (const float*)d_in[0];
    const float* W     = (const float*)d_in[1];
    const float* b     = (const float*)d_in[2];
    const float* lA    = (const float*)d_in[3];
    const float* lB    = (const float*)d_in[4];
    const float* delta = (const float*)d_in[5];
    const int*   mask  = (const int*)d_in[6];
    float* out = (float*)d_out;

    bf16* Weff = (bf16*)d_ws;                                     // 33.5 MB
    bf16* Xb   = (bf16*)((char*)d_ws + (size_t)NDIM * KDIM * 2);  // 67 MB

    const size_t need = (size_t)NDIM * KDIM * 2 + (size_t)MDIM * KDIM * 2;

    if (ws_size >= need) {
        prep<<<dim3(4096), 256, 0, stream>>>(
            W, lA, lB, delta, mask, Weff, x, Xb);
        gemm_bf16<<<dim3(NDIM / 128, MDIM / 128), 256, 0, stream>>>(
            Xb, Weff, b, out);
    } else {
        prep<<<dim3(2048), 256, 0, stream>>>(   // fold only
            W, lA, lB, delta, mask, Weff, x, Xb);
        gemm_f32<<<dim3(NDIM / 128, MDIM / 128), 256, 0, stream>>>(
            x, Weff, b, out);
    }
}

// Round 4
// 610.904 us; speedup vs baseline: 1.1098x; 1.0906x over previous
//
#include <hip/hip_runtime.h>
#include <hip/hip_bf16.h>

typedef __hip_bfloat16 bf16;
typedef __attribute__((ext_vector_type(8))) short bf16x8;   // 8 bf16 = 4 VGPRs
typedef __attribute__((ext_vector_type(4))) float f32x4;
typedef __attribute__((ext_vector_type(4))) int int4v;

#define AS1 __attribute__((address_space(1)))
#define AS3 __attribute__((address_space(3)))

#define MDIM 8192   // B*S
#define NDIM 4096   // D_OUT
#define KDIM 4096   // D_IN
#define SCALING 2.0f

// ---------------------------------------------------------------------------
// prep: fused fold + convert (confirmed ~40 us better than r0's split version).
//   Blocks [0, 2048):    fold Weff = W + s*(lB@lA) + mask?delta  (bf16 out)
//                        block = 16 o-rows x 512 d-cols; lA tile staged in LDS.
//   Blocks [2048, 4096): grid-stride X fp32 -> bf16 convert.
// ---------------------------------------------------------------------------
__global__ __launch_bounds__(256) void prep(
    const float* __restrict__ W, const float* __restrict__ lA,
    const float* __restrict__ lB, const float* __restrict__ delta,
    const int* __restrict__ mask, bf16* __restrict__ Weff,
    const float* __restrict__ X, bf16* __restrict__ Xb)
{
    __shared__ float sA[16 * 512];   // 32 KB -> 5 blocks/CU
    const int bid = blockIdx.x;
    const int tid = threadIdx.x;

    if (bid < 2048) {
        // ---- fold ----
        const int ob = (bid >> 3) * 16;     // o-tile base (256 tiles)
        const int db = (bid & 7) * 512;     // d-tile base (8 tiles)

#pragma unroll
        for (int i = tid; i < 2048; i += 256) {
            const int row = i >> 7;          // 0..15
            const int qc  = (i & 127) * 4;   // 0..508
            *(f32x4*)(sA + row * 512 + qc) =
                *(const f32x4*)(lA + (size_t)row * KDIM + db + qc);
        }
        __syncthreads();

        for (int c = tid; c < 1024; c += 256) {
            const int o_l = c >> 6;              // 0..15 (wave-uniform)
            const int dc  = (c & 63) * 8;        // 0..504
            const int o   = ob + o_l;
            const size_t base = (size_t)o * KDIM + db + dc;

            float Bo[16];
#pragma unroll
            for (int r = 0; r < 16; ++r) Bo[r] = lB[o * 16 + r];

            f32x4 wa = *(const f32x4*)(W + base);
            f32x4 wb = *(const f32x4*)(W + base + 4);
            f32x4 da = *(const f32x4*)(delta + base);
            f32x4 db4 = *(const f32x4*)(delta + base + 4);

            int mk[8];
            *(int4v*)(mk)     = *(const int4v*)(mask + base);
            *(int4v*)(mk + 4) = *(const int4v*)(mask + base + 4);

            float lor[8] = {0.f, 0.f, 0.f, 0.f, 0.f, 0.f, 0.f, 0.f};
#pragma unroll
            for (int r = 0; r < 16; ++r) {
                f32x4 aa = *(const f32x4*)(sA + r * 512 + dc);
                f32x4 ab = *(const f32x4*)(sA + r * 512 + dc + 4);
#pragma unroll
                for (int e = 0; e < 4; ++e) {
                    lor[e]     += Bo[r] * aa[e];
                    lor[e + 4] += Bo[r] * ab[e];
                }
            }

            int4v ov4;
            bf16* ov = (bf16*)&ov4;
#pragma unroll
            for (int e = 0; e < 8; ++e) {
                float w = (e < 4) ? wa[e] : wb[e - 4];
                float d = (e < 4) ? da[e] : db4[e - 4];
                float a = w + SCALING * lor[e];
                if (mk[e]) a += d;
                ov[e] = __float2bfloat16(a);
            }
            *(int4v*)(Weff + base) = ov4;
        }
    } else {
        // ---- convert X (grid-stride, 8 iters/thread) ----
        const size_t nchunk = (size_t)MDIM * KDIM / 8;   // 4,194,304
        for (size_t c = (size_t)(bid - 2048) * 256 + tid; c < nchunk;
             c += (size_t)2048 * 256) {
            const size_t i = c * 8;
            f32x4 a = *(const f32x4*)(X + i);
            f32x4 b = *(const f32x4*)(X + i + 4);
            int4v ov4;
            bf16* ov = (bf16*)&ov4;
#pragma unroll
            for (int e = 0; e < 4; ++e) {
                ov[e]     = __float2bfloat16(a[e]);
                ov[e + 4] = __float2bfloat16(b[e]);
            }
            *(int4v*)(Xb + i) = ov4;
        }
    }
}

// ---------------------------------------------------------------------------
// GEMM (bf16 x bf16 -> fp32): EXACT round-0 kernel (272 us, MfmaUtil 48.6,
// 0 bank conflicts).  Default raster — every remap tried (XCD chunking r3,
// 256^2 8-phase r1/r2) regressed; this structure is at its ceiling.
// 128x128 tile, BK=64, 2x2 waves, 4x4 mfma_f32_16x16x32_bf16.
// global_load_lds width=16; XOR swizzle on 16B chunks -> 0 bank conflicts.
// ---------------------------------------------------------------------------
__global__ __launch_bounds__(256, 4) void gemm_bf16(
    const bf16* __restrict__ X, const bf16* __restrict__ Wt,
    const float* __restrict__ bias, float* __restrict__ out)
{
    __shared__ bf16 As[128 * 64];   // 16 KB
    __shared__ bf16 Bs[128 * 64];   // 16 KB

    const int tid  = threadIdx.x;
    const int lane = tid & 63;
    const int wave = tid >> 6;
    const int wm   = wave & 1;
    const int wn   = wave >> 1;
    const int quad = lane >> 4;
    const int l16  = lane & 15;

    const int bn = blockIdx.x * 128;
    const int bm = blockIdx.y * 128;
    const int cwave = tid & ~63;

    f32x4 acc[4][4];
#pragma unroll
    for (int i = 0; i < 4; ++i)
#pragma unroll
        for (int j = 0; j < 4; ++j)
            acc[i][j] = (f32x4){0.f, 0.f, 0.f, 0.f};

    for (int kt = 0; kt < KDIM / 64; ++kt) {
        const int k0 = kt * 64;
        if (kt) __syncthreads();
#pragma unroll
        for (int j = 0; j < 4; ++j) {
            const int c  = j * 256 + tid;
            const int m  = c >> 3;
            const int kc = (c & 7) ^ (m & 7);
            const int cb = j * 256 + cwave;
            __builtin_amdgcn_global_load_lds(
                (const AS1 void*)(X + (size_t)(bm + m) * KDIM + k0 + kc * 8),
                (AS3 void*)(As + cb * 8), 16, 0, 0);
            __builtin_amdgcn_global_load_lds(
                (const AS1 void*)(Wt + (size_t)(bn + m) * KDIM + k0 + kc * 8),
                (AS3 void*)(Bs + cb * 8), 16, 0, 0);
        }
        __syncthreads();

#pragma unroll
        for (int ks = 0; ks < 2; ++ks) {
            bf16x8 af[4], bfr[4];
#pragma unroll
            for (int i = 0; i < 4; ++i) {
                const int m   = wm * 64 + i * 16 + l16;
                const int kca = (ks * 4 + quad) ^ (m & 7);
                af[i] = *(const bf16x8*)(As + m * 64 + kca * 8);
                const int n   = wn * 64 + i * 16 + l16;
                const int kcb = (ks * 4 + quad) ^ (n & 7);
                bfr[i] = *(const bf16x8*)(Bs + n * 64 + kcb * 8);
            }
#pragma unroll
            for (int i = 0; i < 4; ++i)
#pragma unroll
                for (int j = 0; j < 4; ++j)
                    acc[i][j] = __builtin_amdgcn_mfma_f32_16x16x32_bf16(
                        af[i], bfr[j], acc[i][j], 0, 0, 0);
        }
    }

    // C/D layout: col = lane&15, row = quad*4 + reg
    float bv[4];
#pragma unroll
    for (int j = 0; j < 4; ++j)
        bv[j] = bias[bn + wn * 64 + j * 16 + l16];

#pragma unroll
    for (int i = 0; i < 4; ++i) {
        const int mg = bm + wm * 64 + i * 16 + quad * 4;
#pragma unroll
        for (int j = 0; j < 4; ++j) {
            const int ng = bn + wn * 64 + j * 16 + l16;
#pragma unroll
            for (int r = 0; r < 4; ++r)
                out[(size_t)(mg + r) * NDIM + ng] = acc[i][j][r] + bv[j];
        }
    }
}

// ---------------------------------------------------------------------------
// Fallback GEMM (fp32 X) — used only if ws can't fit the bf16 copy of X.
// ---------------------------------------------------------------------------
__global__ __launch_bounds__(256, 3) void gemm_f32(
    const float* __restrict__ X, const bf16* __restrict__ Wt,
    const float* __restrict__ bias, float* __restrict__ out)
{
    __shared__ float Asf[128 * 64];  // 32 KB
    __shared__ bf16  Bs[128 * 64];   // 16 KB

    const int tid  = threadIdx.x;
    const int lane = tid & 63;
    const int wave = tid >> 6;
    const int wmf  = wave & 1;
    const int wnf  = wave >> 1;
    const int quad = lane >> 4;
    const int l16  = lane & 15;

    const int bn = blockIdx.x * 128;
    const int bm = blockIdx.y * 128;
    const int cwave = tid & ~63;

    f32x4 acc[4][4];
#pragma unroll
    for (int i = 0; i < 4; ++i)
#pragma unroll
        for (int j = 0; j < 4; ++j)
            acc[i][j] = (f32x4){0.f, 0.f, 0.f, 0.f};

    for (int kt = 0; kt < KDIM / 64; ++kt) {
        const int k0 = kt * 64;
        if (kt) __syncthreads();
#pragma unroll
        for (int j = 0; j < 8; ++j) {
            const int c  = j * 256 + tid;
            const int m  = c >> 4;
            const int kc = (c & 15) ^ (m & 15);
            const int cb = j * 256 + cwave;
            __builtin_amdgcn_global_load_lds(
                (const AS1 void*)(X + (size_t)(bm + m) * KDIM + k0 + kc * 4),
                (AS3 void*)(Asf + cb * 4), 16, 0, 0);
        }
#pragma unroll
        for (int j = 0; j < 4; ++j) {
            const int c  = j * 256 + tid;
            const int m  = c >> 3;
            const int kc = (c & 7) ^ (m & 7);
            const int cb = j * 256 + cwave;
            __builtin_amdgcn_global_load_lds(
                (const AS1 void*)(Wt + (size_t)(bn + m) * KDIM + k0 + kc * 8),
                (AS3 void*)(Bs + cb * 8), 16, 0, 0);
        }
        __syncthreads();

#pragma unroll
        for (int ks = 0; ks < 2; ++ks) {
            bf16x8 af[4], bfr[4];
#pragma unroll
            for (int i = 0; i < 4; ++i) {
                const int m  = wmf * 64 + i * 16 + l16;
                const int k2 = (ks * 4 + quad) * 2;
                f32x4 lo = *(const f32x4*)(Asf + m * 64 + ((k2     ^ (m & 15)) * 4));
                f32x4 hi = *(const f32x4*)(Asf + m * 64 + (((k2+1) ^ (m & 15)) * 4));
                bf16 tmp[8];
#pragma unroll
                for (int e = 0; e < 4; ++e) {
                    tmp[e]     = __float2bfloat16(lo[e]);
                    tmp[e + 4] = __float2bfloat16(hi[e]);
                }
                af[i] = *(const bf16x8*)tmp;

                const int n   = wnf * 64 + i * 16 + l16;
                const int kcb = (ks * 4 + quad) ^ (n & 7);
                bfr[i] = *(const bf16x8*)(Bs + n * 64 + kcb * 8);
            }
#pragma unroll
            for (int i = 0; i < 4; ++i)
#pragma unroll
                for (int j = 0; j < 4; ++j)
                    acc[i][j] = __builtin_amdgcn_mfma_f32_16x16x32_bf16(
                        af[i], bfr[j], acc[i][j], 0, 0, 0);
        }
    }

    float bv[4];
#pragma unroll
    for (int j = 0; j < 4; ++j)
        bv[j] = bias[bn + wnf * 64 + j * 16 + l16];

#pragma unroll
    for (int i = 0; i < 4; ++i) {
        const int mg = bm + wmf * 64 + i * 16 + quad * 4;
#pragma unroll
        for (int j = 0; j < 4; ++j) {
            const int ng = bn + wnf * 64 + j * 16 + l16;
#pragma unroll
            for (int r = 0; r < 4; ++r)
                out[(size_t)(mg + r) * NDIM + ng] = acc[i][j][r] + bv[j];
        }
    }
}

// ---------------------------------------------------------------------------
extern "C" void kernel_launch(void* const* d_in, const int* in_sizes, int n_in,
                              void* d_out, int out_size, void* d_ws, size_t ws_size,
                              hipStream_t stream)
{
    const float* x     = (const float*)d_in[0];
    const float* W     = (const float*)d_in[1];
    const float* b     = (const float*)d_in[2];
    const float* lA    = (const float*)d_in[3];
    const float* lB    = (const float*)d_in[4];
    const float* delta = (const float*)d_in[5];
    const int*   mask  = (const int*)d_in[6];
    float* out = (float*)d_out;

    bf16* Weff = (bf16*)d_ws;                                     // 33.5 MB
    bf16* Xb   = (bf16*)((char*)d_ws + (size_t)NDIM * KDIM * 2);  // 67 MB

    const size_t need = (size_t)NDIM * KDIM * 2 + (size_t)MDIM * KDIM * 2;

    if (ws_size >= need) {
        prep<<<dim3(4096), 256, 0, stream>>>(
            W, lA, lB, delta, mask, Weff, x, Xb);
        gemm_bf16<<<dim3(NDIM / 128, MDIM / 128), 256, 0, stream>>>(
            Xb, Weff, b, out);
    } else {
        prep<<<dim3(2048), 256, 0, stream>>>(   // fold only
            W, lA, lB, delta, mask, Weff, x, Xb);
        gemm_f32<<<dim3(NDIM / 128, MDIM / 128), 256, 0, stream>>>(
            x, Weff, b, out);
    }
}

// Round 5
// 610.406 us; speedup vs baseline: 1.1107x; 1.0008x over previous
//
#include <hip/hip_runtime.h>
#include <hip/hip_bf16.h>

typedef __hip_bfloat16 bf16;
typedef __attribute__((ext_vector_type(8))) short bf16x8;   // 8 bf16 = 4 VGPRs
typedef __attribute__((ext_vector_type(4))) float f32x4;
typedef __attribute__((ext_vector_type(4))) int int4v;

#define AS1 __attribute__((address_space(1)))
#define AS3 __attribute__((address_space(3)))

#define MDIM 8192   // B*S
#define NDIM 4096   // D_OUT
#define KDIM 4096   // D_IN
#define SCALING 2.0f

// ---------------------------------------------------------------------------
// prep: fused fold + convert, register-reuse version (NO LDS).
//   Blocks [0, 2048):    fold Weff = W + s*(lB@lA) + mask?delta  (bf16 out).
//     Old version staged lA in LDS but every ds_read_b128 had lane-stride
//     8 words -> bank start (lane*8)%32 in {0,8,16,24}: 16-way aliasing,
//     ~5x LDS serialization.  New version: each thread owns 4 o-rows x one
//     8-wide d-chunk; lA row-slices are read once from L2 (coalesced, 2 MB
//     resident) and reused 4x in registers via Bo[4][16].  No LDS, no
//     __syncthreads, 512 FMA/thread.
//   Blocks [2048, 4096): grid-stride X fp32 -> bf16 convert.
// ---------------------------------------------------------------------------
__global__ __launch_bounds__(256) void prep(
    const float* __restrict__ W, const float* __restrict__ lA,
    const float* __restrict__ lB, const float* __restrict__ delta,
    const int* __restrict__ mask, bf16* __restrict__ Weff,
    const float* __restrict__ X, bf16* __restrict__ Xb)
{
    const int bid = blockIdx.x;
    const int tid = threadIdx.x;

    if (bid < 2048) {
        // ---- fold: block = 16 o-rows x 512 d-cols ----
        const int ob    = (bid >> 3) * 16;          // o-tile base (256 tiles)
        const int db    = (bid & 7) * 512;          // d-tile base (8 tiles)
        const int obase = ob + (tid >> 6) * 4;      // wave -> 4 o-rows
        const int dc    = db + (tid & 63) * 8;      // 2 KB contiguous per wave

        float Bo[4][16];
#pragma unroll
        for (int oo = 0; oo < 4; ++oo)
#pragma unroll
            for (int r = 0; r < 16; ++r)
                Bo[oo][r] = lB[(obase + oo) * 16 + r];

        float lor[4][8];
#pragma unroll
        for (int oo = 0; oo < 4; ++oo)
#pragma unroll
            for (int e = 0; e < 8; ++e) lor[oo][e] = 0.f;

#pragma unroll
        for (int r = 0; r < 16; ++r) {
            f32x4 aa = *(const f32x4*)(lA + (size_t)r * KDIM + dc);
            f32x4 ab = *(const f32x4*)(lA + (size_t)r * KDIM + dc + 4);
#pragma unroll
            for (int oo = 0; oo < 4; ++oo)
#pragma unroll
                for (int e = 0; e < 4; ++e) {
                    lor[oo][e]     += Bo[oo][r] * aa[e];
                    lor[oo][e + 4] += Bo[oo][r] * ab[e];
                }
        }

#pragma unroll
        for (int oo = 0; oo < 4; ++oo) {
            const size_t base = (size_t)(obase + oo) * KDIM + dc;

            f32x4 wa  = *(const f32x4*)(W + base);
            f32x4 wb  = *(const f32x4*)(W + base + 4);
            f32x4 da  = *(const f32x4*)(delta + base);
            f32x4 db4 = *(const f32x4*)(delta + base + 4);

            int mk[8];
            *(int4v*)(mk)     = *(const int4v*)(mask + base);
            *(int4v*)(mk + 4) = *(const int4v*)(mask + base + 4);

            int4v ov4;
            bf16* ov = (bf16*)&ov4;
#pragma unroll
            for (int e = 0; e < 8; ++e) {
                float w = (e < 4) ? wa[e] : wb[e - 4];
                float d = (e < 4) ? da[e] : db4[e - 4];
                float a = w + SCALING * lor[oo][e];
                if (mk[e]) a += d;
                ov[e] = __float2bfloat16(a);
            }
            *(int4v*)(Weff + base) = ov4;
        }
    } else {
        // ---- convert X (grid-stride, 8 iters/thread) ----
        const size_t nchunk = (size_t)MDIM * KDIM / 8;   // 4,194,304
        for (size_t c = (size_t)(bid - 2048) * 256 + tid; c < nchunk;
             c += (size_t)2048 * 256) {
            const size_t i = c * 8;
            f32x4 a = *(const f32x4*)(X + i);
            f32x4 b = *(const f32x4*)(X + i + 4);
            int4v ov4;
            bf16* ov = (bf16*)&ov4;
#pragma unroll
            for (int e = 0; e < 4; ++e) {
                ov[e]     = __float2bfloat16(a[e]);
                ov[e + 4] = __float2bfloat16(b[e]);
            }
            *(int4v*)(Xb + i) = ov4;
        }
    }
}

// ---------------------------------------------------------------------------
// GEMM (bf16 x bf16 -> fp32): EXACT round-0/round-4 kernel (271.5 us,
// MfmaUtil 47.5, 0 bank conflicts).  Every structural remap tried (XCD
// chunking r3, 256^2 8-phase r1/r2) regressed; pinned at the m97-structure
// ceiling (1014 TF at this shape).  DO NOT MODIFY.
// 128x128 tile, BK=64, 2x2 waves, 4x4 mfma_f32_16x16x32_bf16.
// ---------------------------------------------------------------------------
__global__ __launch_bounds__(256, 4) void gemm_bf16(
    const bf16* __restrict__ X, const bf16* __restrict__ Wt,
    const float* __restrict__ bias, float* __restrict__ out)
{
    __shared__ bf16 As[128 * 64];   // 16 KB
    __shared__ bf16 Bs[128 * 64];   // 16 KB

    const int tid  = threadIdx.x;
    const int lane = tid & 63;
    const int wave = tid >> 6;
    const int wm   = wave & 1;
    const int wn   = wave >> 1;
    const int quad = lane >> 4;
    const int l16  = lane & 15;

    const int bn = blockIdx.x * 128;
    const int bm = blockIdx.y * 128;
    const int cwave = tid & ~63;

    f32x4 acc[4][4];
#pragma unroll
    for (int i = 0; i < 4; ++i)
#pragma unroll
        for (int j = 0; j < 4; ++j)
            acc[i][j] = (f32x4){0.f, 0.f, 0.f, 0.f};

    for (int kt = 0; kt < KDIM / 64; ++kt) {
        const int k0 = kt * 64;
        if (kt) __syncthreads();
#pragma unroll
        for (int j = 0; j < 4; ++j) {
            const int c  = j * 256 + tid;
            const int m  = c >> 3;
            const int kc = (c & 7) ^ (m & 7);
            const int cb = j * 256 + cwave;
            __builtin_amdgcn_global_load_lds(
                (const AS1 void*)(X + (size_t)(bm + m) * KDIM + k0 + kc * 8),
                (AS3 void*)(As + cb * 8), 16, 0, 0);
            __builtin_amdgcn_global_load_lds(
                (const AS1 void*)(Wt + (size_t)(bn + m) * KDIM + k0 + kc * 8),
                (AS3 void*)(Bs + cb * 8), 16, 0, 0);
        }
        __syncthreads();

#pragma unroll
        for (int ks = 0; ks < 2; ++ks) {
            bf16x8 af[4], bfr[4];
#pragma unroll
            for (int i = 0; i < 4; ++i) {
                const int m   = wm * 64 + i * 16 + l16;
                const int kca = (ks * 4 + quad) ^ (m & 7);
                af[i] = *(const bf16x8*)(As + m * 64 + kca * 8);
                const int n   = wn * 64 + i * 16 + l16;
                const int kcb = (ks * 4 + quad) ^ (n & 7);
                bfr[i] = *(const bf16x8*)(Bs + n * 64 + kcb * 8);
            }
#pragma unroll
            for (int i = 0; i < 4; ++i)
#pragma unroll
                for (int j = 0; j < 4; ++j)
                    acc[i][j] = __builtin_amdgcn_mfma_f32_16x16x32_bf16(
                        af[i], bfr[j], acc[i][j], 0, 0, 0);
        }
    }

    // C/D layout: col = lane&15, row = quad*4 + reg
    float bv[4];
#pragma unroll
    for (int j = 0; j < 4; ++j)
        bv[j] = bias[bn + wn * 64 + j * 16 + l16];

#pragma unroll
    for (int i = 0; i < 4; ++i) {
        const int mg = bm + wm * 64 + i * 16 + quad * 4;
#pragma unroll
        for (int j = 0; j < 4; ++j) {
            const int ng = bn + wn * 64 + j * 16 + l16;
#pragma unroll
            for (int r = 0; r < 4; ++r)
                out[(size_t)(mg + r) * NDIM + ng] = acc[i][j][r] + bv[j];
        }
    }
}

// ---------------------------------------------------------------------------
// Fallback GEMM (fp32 X) — used only if ws can't fit the bf16 copy of X.
// ---------------------------------------------------------------------------
__global__ __launch_bounds__(256, 3) void gemm_f32(
    const float* __restrict__ X, const bf16* __restrict__ Wt,
    const float* __restrict__ bias, float* __restrict__ out)
{
    __shared__ float Asf[128 * 64];  // 32 KB
    __shared__ bf16  Bs[128 * 64];   // 16 KB

    const int tid  = threadIdx.x;
    const int lane = tid & 63;
    const int wave = tid >> 6;
    const int wmf  = wave & 1;
    const int wnf  = wave >> 1;
    const int quad = lane >> 4;
    const int l16  = lane & 15;

    const int bn = blockIdx.x * 128;
    const int bm = blockIdx.y * 128;
    const int cwave = tid & ~63;

    f32x4 acc[4][4];
#pragma unroll
    for (int i = 0; i < 4; ++i)
#pragma unroll
        for (int j = 0; j < 4; ++j)
            acc[i][j] = (f32x4){0.f, 0.f, 0.f, 0.f};

    for (int kt = 0; kt < KDIM / 64; ++kt) {
        const int k0 = kt * 64;
        if (kt) __syncthreads();
#pragma unroll
        for (int j = 0; j < 8; ++j) {
            const int c  = j * 256 + tid;
            const int m  = c >> 4;
            const int kc = (c & 15) ^ (m & 15);
            const int cb = j * 256 + cwave;
            __builtin_amdgcn_global_load_lds(
                (const AS1 void*)(X + (size_t)(bm + m) * KDIM + k0 + kc * 4),
                (AS3 void*)(Asf + cb * 4), 16, 0, 0);
        }
#pragma unroll
        for (int j = 0; j < 4; ++j) {
            const int c  = j * 256 + tid;
            const int m  = c >> 3;
            const int kc = (c & 7) ^ (m & 7);
            const int cb = j * 256 + cwave;
            __builtin_amdgcn_global_load_lds(
                (const AS1 void*)(Wt + (size_t)(bn + m) * KDIM + k0 + kc * 8),
                (AS3 void*)(Bs + cb * 8), 16, 0, 0);
        }
        __syncthreads();

#pragma unroll
        for (int ks = 0; ks < 2; ++ks) {
            bf16x8 af[4], bfr[4];
#pragma unroll
            for (int i = 0; i < 4; ++i) {
                const int m  = wmf * 64 + i * 16 + l16;
                const int k2 = (ks * 4 + quad) * 2;
                f32x4 lo = *(const f32x4*)(Asf + m * 64 + ((k2     ^ (m & 15)) * 4));
                f32x4 hi = *(const f32x4*)(Asf + m * 64 + (((k2+1) ^ (m & 15)) * 4));
                bf16 tmp[8];
#pragma unroll
                for (int e = 0; e < 4; ++e) {
                    tmp[e]     = __float2bfloat16(lo[e]);
                    tmp[e + 4] = __float2bfloat16(hi[e]);
                }
                af[i] = *(const bf16x8*)tmp;

                const int n   = wnf * 64 + i * 16 + l16;
                const int kcb = (ks * 4 + quad) ^ (n & 7);
                bfr[i] = *(const bf16x8*)(Bs + n * 64 + kcb * 8);
            }
#pragma unroll
            for (int i = 0; i < 4; ++i)
#pragma unroll
                for (int j = 0; j < 4; ++j)
                    acc[i][j] = __builtin_amdgcn_mfma_f32_16x16x32_bf16(
                        af[i], bfr[j], acc[i][j], 0, 0, 0);
        }
    }

    float bv[4];
#pragma unroll
    for (int j = 0; j < 4; ++j)
        bv[j] = bias[bn + wnf * 64 + j * 16 + l16];

#pragma unroll
    for (int i = 0; i < 4; ++i) {
        const int mg = bm + wmf * 64 + i * 16 + quad * 4;
#pragma unroll
        for (int j = 0; j < 4; ++j) {
            const int ng = bn + wnf * 64 + j * 16 + l16;
#pragma unroll
            for (int r = 0; r < 4; ++r)
                out[(size_t)(mg + r) * NDIM + ng] = acc[i][j][r] + bv[j];
        }
    }
}

// ---------------------------------------------------------------------------
extern "C" void kernel_launch(void* const* d_in, const int* in_sizes, int n_in,
                              void* d_out, int out_size, void* d_ws, size_t ws_size,
                              hipStream_t stream)
{
    const float* x     = (const float*)d_in[0];
    const float* W     = (const float*)d_in[1];
    const float* b     = (const float*)d_in[2];
    const float* lA    = (const float*)d_in[3];
    const float* lB    = (const float*)d_in[4];
    const float* delta = (const float*)d_in[5];
    const int*   mask  = (const int*)d_in[6];
    float* out = (float*)d_out;

    bf16* Weff = (bf16*)d_ws;                                     // 33.5 MB
    bf16* Xb   = (bf16*)((char*)d_ws + (size_t)NDIM * KDIM * 2);  // 67 MB

    const size_t need = (size_t)NDIM * KDIM * 2 + (size_t)MDIM * KDIM * 2;

    if (ws_size >= need) {
        prep<<<dim3(4096), 256, 0, stream>>>(
            W, lA, lB, delta, mask, Weff, x, Xb);
        gemm_bf16<<<dim3(NDIM / 128, MDIM / 128), 256, 0, stream>>>(
            Xb, Weff, b, out);
    } else {
        prep<<<dim3(2048), 256, 0, stream>>>(   // fold only
            W, lA, lB, delta, mask, Weff, x, Xb);
        gemm_f32<<<dim3(NDIM / 128, MDIM / 128), 256, 0, stream>>>(
            x, Weff, b, out);
    }
}